// Round 16
// baseline (67960.931 us; speedup 1.0000x reference)
//
#include <hip/hip_runtime.h>
#include <stdint.h>

#define DEV static __device__ __forceinline__

namespace {
constexpr int Bx = 16, ENCx = 512, DECx = 800, Dx = 256, Hx = 1024;
constexpr int NGATE = 128, NCHAIN = 32, NBLK = NGATE + NCHAIN, NTHR = 512;

// ---- workspace float offsets ----
constexpr int WS_HBH  = 0;                 // 2 buf x 16384 ushort (bf16 h)
constexpr int WS_CTXH = WS_HBH + 16384;    // 2 buf x 8192 ushort (bf16 ctx|nctx)
constexpr int WS_X1M  = WS_CTXH + 8192;    // 2 x [16][256] fp32
constexpr int WS_FEND = WS_X1M + 8192;
// ---- int offsets (relative to wsf + WS_FEND) ----
constexpr int IW_HSLOT = 0;                // 128 slots
constexpr int IW_XSLOT = 128;              // 128 slots
constexpr int IW_CSLOT = 256;              // 32 slots (pad 64)
constexpr int IW_HRDY  = 320;              // 8 replicas stride 16
constexpr int IW_XRDY  = 448;
constexpr int IW_CRDY  = 576;
constexpr int IW_END   = 704;
// ---- packed read-only data (float-slot offsets) ----
constexpr int WS_WIHB = WS_FEND + 768;               // 4096 rows x 384 uints (bf16 Wih)
constexpr int WS_ENCB = WS_WIHB + 4096*384;          // 16*512*128 uints (bf16 enc, d-pairs)
constexpr int WS_TOT  = WS_ENCB + 16*512*128;        // ~10.6 MB total
constexpr size_t CTXOUT = (size_t)Bx*DECx*Dx;

// ---- dynamic LDS float offsets ----
constexpr int LH_STR = 1028;               // padded h stride (fp32)
constexpr int CT_STR = 260;                // padded ctx stride
constexpr int LW_H   = 0;                  // 16*1028 fp32
constexpr int LW_WHH = LW_H + 16*LH_STR;   // 32 rows x 512 uints (bf16 Whh)
constexpr int LDS_DYN_F = LW_WHH + 16384;
constexpr size_t SMEM_BYTES = (size_t)LDS_DYN_F * 4;   // 131,328 B
}

DEV float frcp(float x){ return __builtin_amdgcn_rcpf(x); }
DEV float sigm(float x){ return frcp(1.0f + __expf(-x)); }
DEV float ftanh(float x){
  x = fminf(fmaxf(x, -15.0f), 15.0f);
  float e = __expf(2.0f*x);
  return (e - 1.0f) * frcp(e + 1.0f);
}
DEV float wred16(float v){
  v += __shfl_xor(v, 1); v += __shfl_xor(v, 2);
  v += __shfl_xor(v, 4); v += __shfl_xor(v, 8);
  return v;
}
DEV int   ld_rlx(const int* p){ return __hip_atomic_load(p, __ATOMIC_RELAXED, __HIP_MEMORY_SCOPE_AGENT); }
DEV unsigned ld_rlx_u32(const unsigned* p){ return __hip_atomic_load(p, __ATOMIC_RELAXED, __HIP_MEMORY_SCOPE_AGENT); }
DEV void  st_rlx(int* p, int v){ __hip_atomic_store(p, v, __ATOMIC_RELAXED, __HIP_MEMORY_SCOPE_AGENT); }
DEV void  st_rlx_u32(unsigned* p, unsigned v){ __hip_atomic_store(p, v, __ATOMIC_RELAXED, __HIP_MEMORY_SCOPE_AGENT); }
DEV float ldf_c(const float* p){ return __hip_atomic_load(p, __ATOMIC_RELAXED, __HIP_MEMORY_SCOPE_AGENT); }
DEV void  stf_c(float* p, float v){ __hip_atomic_store(p, v, __ATOMIC_RELAXED, __HIP_MEMORY_SCOPE_AGENT); }
DEV void cbar(){ asm volatile("" ::: "memory"); }

// bf16 pack (round-nearest-even) / unpack (exact shift)
DEV unsigned pack_bf16(float lo, float hi){
  unsigned a = __builtin_bit_cast(unsigned, lo);
  unsigned b = __builtin_bit_cast(unsigned, hi);
  a += 0x7FFFu + ((a >> 16) & 1u);
  b += 0x7FFFu + ((b >> 16) & 1u);
  return (a >> 16) | (b & 0xFFFF0000u);
}
DEV float bflo(unsigned w){ return __builtin_bit_cast(float, w << 16); }
DEV float bfhi(unsigned w){ return __builtin_bit_cast(float, w & 0xFFFF0000u); }
DEV float4 bf4(uint2 w){
  float4 r; r.x = bflo(w.x); r.y = bfhi(w.x); r.z = bflo(w.y); r.w = bfhi(w.y); return r;
}

// sc1 bulk loads: issue + wait inside one asm block
DEV void ld4_wait(float4 (&r)[4], const float* p){
  const float *a1=p+2048,*a2=p+4096,*a3=p+6144;
  asm volatile(
    "global_load_dwordx4 %0, %4, off sc1\n\t"
    "global_load_dwordx4 %1, %5, off sc1\n\t"
    "global_load_dwordx4 %2, %6, off sc1\n\t"
    "global_load_dwordx4 %3, %7, off sc1\n\t"
    "s_waitcnt vmcnt(0)"
    : "=&v"(r[0]),"=&v"(r[1]),"=&v"(r[2]),"=&v"(r[3])
    : "v"(p),"v"(a1),"v"(a2),"v"(a3)
    : "memory");
}
DEV void ld2_wait(float4 (&r)[2], const float* p){
  const float *a1=p+2048;
  asm volatile(
    "global_load_dwordx4 %0, %2, off sc1\n\t"
    "global_load_dwordx4 %1, %3, off sc1\n\t"
    "s_waitcnt vmcnt(0)"
    : "=&v"(r[0]),"=&v"(r[1])
    : "v"(p),"v"(a1)
    : "memory");
}
DEV int4 ld4i_sc1(const int* p){
  int4 r;
  asm volatile("global_load_dwordx4 %0, %1, off sc1\n\ts_waitcnt vmcnt(0)"
    : "=&v"(r) : "v"(p) : "memory");
  return r;
}

// waiter: wave0 polls its replica, stamps LDS; other waves spin LDS
DEV void wait_rdy(int* rdy8, int repl, int target, volatile int* lslot){
  const int tid = threadIdx.x;
  if (tid < 64){
    while (ld_rlx(rdy8 + repl*16) < target) __builtin_amdgcn_s_sleep(8);
    if (tid == 0) *lslot = target;
  } else {
    while (*lslot < target) __builtin_amdgcn_s_sleep(1);
  }
  __syncthreads();
  cbar();
}

// detector: wave0 scans nq*4 slots with dwordx4, then publishes 8 replicas
DEV void detect_pub(int* slots, int nq, int* rdy8, int target, volatile int* lslot){
  const int tid = threadIdx.x;
  if (tid < 64){
    const int* my = slots + tid*4;
    const bool active = (tid < nq);
    for (;;){
      bool ok = true;
      if (active){
        int4 v = ld4i_sc1(my);
        ok = (v.x >= target) & (v.y >= target) & (v.z >= target) & (v.w >= target);
      }
      if (__ballot(ok) == ~0ull) break;
      __builtin_amdgcn_s_sleep(8);
    }
    if (tid < 8) st_rlx(rdy8 + tid*16, target);
    if (tid == 0) *lslot = target;
  } else {
    while (*lslot < target) __builtin_amdgcn_s_sleep(1);
  }
  __syncthreads();
  cbar();
}

// init + one-time bf16 packing of Wih and enc (kernel boundary = coherence)
extern "C" __global__ void gmm_init(const float* __restrict__ Wih,
                                    const float* __restrict__ enc,
                                    float* __restrict__ wsf){
  int* wsi = (int*)(wsf + WS_FEND);
  unsigned* wihb = (unsigned*)(wsf + WS_WIHB);
  unsigned* encb = (unsigned*)(wsf + WS_ENCB);
  int idx = blockIdx.x*blockDim.x + threadIdx.x;
  int n = gridDim.x*blockDim.x;
  for (int k = idx; k < IW_END; k += n) wsi[k] = 0;
  for (int i = idx; i < 4096*384; i += n){
    int row = i / 384, c = i % 384;
    wihb[i] = pack_bf16(Wih[(size_t)row*768 + 2*c], Wih[(size_t)row*768 + 2*c + 1]);
  }
  for (int i = idx; i < 16*512*128; i += n){
    int j = i & 127, e = (i >> 7) & 511, b = i >> 16;
    const float* s = enc + ((size_t)b*512 + e)*256 + 2*j;
    encb[i] = pack_bf16(s[0], s[1]);
  }
}

extern "C" __global__ void __launch_bounds__(NTHR, 1) gmm_main(
    const float* __restrict__ enc, const float* __restrict__ mel,
    const int* __restrict__ outlen, const int* __restrict__ condlen,
    const float* __restrict__ Wih, const float* __restrict__ Whh,
    const float* __restrict__ bih, const float* __restrict__ bhh,
    const float* __restrict__ W1,  const float* __restrict__ b1v,
    const float* __restrict__ W2,  const float* __restrict__ Wlin,
    const float* __restrict__ blin,
    float* __restrict__ out, float* __restrict__ wsf)
{
  const int bk = blockIdx.x, tid = threadIdx.x;
  const int klane4 = (tid & 15) * 4;
  const int b4 = (tid >> 4) & 3;
  const int wid = tid >> 6;

  int* wsi   = (int*)(wsf + WS_FEND);
  int* hslot = wsi + IW_HSLOT;
  int* xslot = wsi + IW_XSLOT;
  int* cslot = wsi + IW_CSLOT;
  int* hrdy  = wsi + IW_HRDY;
  int* crdy  = wsi + IW_CRDY;
  unsigned short* hbh = (unsigned short*)(wsf + WS_HBH);
  unsigned* ctx32u    = (unsigned*)(wsf + WS_CTXH);
  float* x1m = wsf + WS_X1M;
  const unsigned* wsWihB = (const unsigned*)(wsf + WS_WIHB);
  const unsigned* wsEncB = (const unsigned*)(wsf + WS_ENCB);

  extern __shared__ float lds[];
  float*    lh      = lds + LW_H;
  unsigned* lwhh_u  = (unsigned*)(lds + LW_WHH);
  const uint2* lwhh2 = (const uint2*)(lds + LW_WHH);

  __shared__ float g_lds[512];
  __shared__ float bsum[32];
  __shared__ float cl[128];
  __shared__ float hstg[128];
  __shared__ float x1l[256];
  __shared__ float x2p[512];
  __shared__ float x2l[256];
  __shared__ float outp[384];
  __shared__ float outl[24];
  __shared__ float mixw[8], mixlc[8], mixis[8];
  __shared__ float locl[8];
  __shared__ float albl[512];
  __shared__ float cpn[2][4][128];
  __shared__ int   s_cond, s_olen;
  __shared__ int   lfh, lfx, lfc;

  if (tid == 0){ lfh = 0; lfx = 0; lfc = 0; }

  const bool is_gate = (bk < NGATE);
  const int  cid = bk - NGATE;
  const int  cb  = cid >> 1;
  const int  hf2 = cid & 1;
  const int  repl = bk & 7;

  // gate: local rows r (0..31): global gate row = (r>>3)*1024 + bk*8 + (r&7)
  const int r0 = wid*4;
  const unsigned* wihb[4];
  if (is_gate){
    #pragma unroll
    for (int r = 0; r < 4; ++r){
      int lr = r0 + r;
      wihb[r] = wsWihB + (size_t)((lr>>3)*1024 + bk*8 + (lr&7))*384;
    }
  }

  // ---------------- one-time staging ----------------
  float4 w2r[32];
  if (is_gate){
    for (int i = tid; i < 16384; i += NTHR){
      int r = i >> 9, c = i & 511;
      size_t gr = (size_t)((r>>3)*1024 + bk*8 + (r&7));
      lwhh_u[i] = pack_bf16(Whh[gr*1024 + 2*c], Whh[gr*1024 + 2*c + 1]);
    }
    if (tid < 32){
      int g = tid >> 3, u = bk*8 + (tid & 7);
      bsum[tid] = bih[g*1024 + u] + bhh[g*1024 + u];
    }
  } else {
    if (tid == 0){ s_cond = condlen[cb]; s_olen = outlen[cb]; }
    if (tid < 8) locl[tid] = -0.1f;
    int r = tid >> 1, hf = tid & 1;
    const float* w2row = W2 + (size_t)r*256 + hf*128;
    #pragma unroll
    for (int i = 0; i < 32; ++i) w2r[i] = *reinterpret_cast<const float4*>(w2row + i*4);
  }
  __syncthreads();

  // gates: stage bf16 h master -> LDS fp32
  auto write_h = [&](int t){
    float4 r[4];
    ld4_wait(r, (const float*)(hbh + (t & 1)*16384) + tid*4);
    #pragma unroll
    for (int i = 0; i < 4; ++i){
      unsigned wx = __builtin_bit_cast(unsigned, r[i].x);
      unsigned wy = __builtin_bit_cast(unsigned, r[i].y);
      unsigned wz = __builtin_bit_cast(unsigned, r[i].z);
      unsigned ww = __builtin_bit_cast(unsigned, r[i].w);
      int b = i*4 + (tid >> 7);
      float* d = lh + b*LH_STR + (tid & 127)*8;
      d[0] = bflo(wx); d[1] = bfhi(wx); d[2] = bflo(wy); d[3] = bfhi(wy);
      d[4] = bflo(wz); d[5] = bfhi(wz); d[6] = bflo(ww); d[7] = bfhi(ww);
    }
    __syncthreads();
  };

  // gate reduce + cell + bf16 h publish
  auto cell_and_publish = [&](float (&acc)[4][4], int bsel, int stamp, bool first){
    #pragma unroll
    for (int r = 0; r < 4; ++r)
      #pragma unroll
      for (int bi = 0; bi < 4; ++bi){
        float v = wred16(acc[r][bi]);
        if ((tid & 15) == 0) g_lds[(r0 + r)*16 + b4*4 + bi] = v;
      }
    __syncthreads();
    if (tid < 128){
      int u = tid >> 4, b = tid & 15;
      float gi = g_lds[( 0 + u)*16 + b] + bsum[u];
      float gg = g_lds[(16 + u)*16 + b] + bsum[16 + u];
      float go = g_lds[(24 + u)*16 + b] + bsum[24 + u];
      float c2;
      if (first){
        c2 = sigm(gi) * ftanh(gg);
      } else {
        float gf = g_lds[(8 + u)*16 + b] + bsum[8 + u];
        c2 = sigm(gf)*cl[tid] + sigm(gi)*ftanh(gg);
      }
      float h2 = sigm(go)*ftanh(c2);
      cl[tid] = c2;
      hstg[u*16 + b] = h2;
    }
    __syncthreads();
    if (tid < 64){
      int p = tid >> 4, b = tid & 15;
      unsigned w = pack_bf16(hstg[(2*p)*16 + b], hstg[(2*p + 1)*16 + b]);
      st_rlx_u32((unsigned*)hbh + bsel*8192 + b*512 + bk*4 + p, w);
    }
    __syncthreads();
    if (tid == 0) st_rlx(hslot + bk, stamp);
  };

  // ---------------- prologue: gates t=0 -> h_0 ----------------
  if (is_gate){
    float acc[4][4] = {};
    #pragma unroll
    for (int it = 0; it < 4; ++it){
      int k = it*64 + klane4;
      float4 wv[4];
      #pragma unroll
      for (int r = 0; r < 4; ++r) wv[r] = bf4(*reinterpret_cast<const uint2*>(wihb[r] + (k>>1)));
      #pragma unroll
      for (int bi = 0; bi < 4; ++bi){
        float4 xv = *reinterpret_cast<const float4*>(mel + (size_t)(b4*4 + bi)*DECx*Dx + k);
        #pragma unroll
        for (int r = 0; r < 4; ++r)
          acc[r][bi] = fmaf(wv[r].x,xv.x, fmaf(wv[r].y,xv.y, fmaf(wv[r].z,xv.z, fmaf(wv[r].w,xv.w, acc[r][bi]))));
      }
    }
    #pragma unroll
    for (int it = 0; it < 4; ++it){
      int k = it*64 + klane4;
      float4 wv[4];
      #pragma unroll
      for (int r = 0; r < 4; ++r) wv[r] = bf4(*reinterpret_cast<const uint2*>(wihb[r] + 256 + (k>>1)));
      #pragma unroll
      for (int bi = 0; bi < 4; ++bi){
        float4 xv = *reinterpret_cast<const float4*>(enc + (size_t)(b4*4 + bi)*ENCx*Dx + k);
        #pragma unroll
        for (int r = 0; r < 4; ++r)
          acc[r][bi] = fmaf(wv[r].x,xv.x, fmaf(wv[r].y,xv.y, fmaf(wv[r].z,xv.z, fmaf(wv[r].w,xv.w, acc[r][bi]))));
      }
    }
    cell_and_publish(acc, 0, 1, true);
  }

  // ---------------- main loop ----------------
  for (int t = 0; t < DECx; ++t){
    const int par = t & 1;
    const bool last = (t == DECx - 1);

    if (is_gate){
      // convoy h: detector = gate bk0
      if (bk == 0) detect_pub(hslot, 32, hrdy, t + 1, &lfh);
      else         wait_rdy(hrdy, repl, t + 1, &lfh);
      write_h(t);

      // x1 rows 2bk, 2bk+1 (h local; W1 rows tiny, L2-resident)
      {
        int row = tid >> 8;
        int b = (tid >> 4) & 15, kl = tid & 15;
        const float* W1r = W1 + (size_t)(2*bk + row)*1024;
        float a = 0.f;
        #pragma unroll
        for (int it = 0; it < 16; ++it){
          int k = it*64 + kl*4;
          float4 wv = *reinterpret_cast<const float4*>(W1r + k);
          float4 xv = *reinterpret_cast<const float4*>(lh + (size_t)b*LH_STR + k);
          a = fmaf(wv.x,xv.x, fmaf(wv.y,xv.y, fmaf(wv.z,xv.z, fmaf(wv.w,xv.w, a))));
        }
        a = wred16(a);
        if (kl == 0){
          a += b1v[2*bk + row];
          a = (a >= 0.f) ? a : 0.1f*a;
          stf_c(x1m + par*4096 + b*256 + 2*bk + row, a);
        }
      }
      __syncthreads();
      if (tid == 0) st_rlx(xslot + bk, t + 1);

      // region 1 (overlaps chain): mel_{t+1} bf16-Wih + Whh(bf16 LDS) @ h_t
      float acc[4][4] = {};
      if (!last){
        const int tt = t + 1;
        #pragma unroll
        for (int it = 0; it < 4; ++it){
          int k = it*64 + klane4;
          float4 wv[4];
          #pragma unroll
          for (int r = 0; r < 4; ++r) wv[r] = bf4(*reinterpret_cast<const uint2*>(wihb[r] + (k>>1)));
          #pragma unroll
          for (int bi = 0; bi < 4; ++bi){
            float4 xv = *reinterpret_cast<const float4*>(mel + ((size_t)(b4*4 + bi)*DECx + tt)*Dx + k);
            #pragma unroll
            for (int r = 0; r < 4; ++r)
              acc[r][bi] = fmaf(wv[r].x,xv.x, fmaf(wv[r].y,xv.y, fmaf(wv[r].z,xv.z, fmaf(wv[r].w,xv.w, acc[r][bi]))));
          }
        }
        #pragma unroll 4
        for (int it = 0; it < 16; ++it){
          int k = it*64 + klane4;
          uint2 wv2[4];
          #pragma unroll
          for (int r = 0; r < 4; ++r) wv2[r] = lwhh2[(size_t)(r0 + r)*256 + it*16 + (tid & 15)];
          #pragma unroll
          for (int bi = 0; bi < 4; ++bi){
            float4 xv = *reinterpret_cast<const float4*>(lh + (size_t)(b4*4 + bi)*LH_STR + k);
            #pragma unroll
            for (int r = 0; r < 4; ++r){
              float w0 = bflo(wv2[r].x), w1 = bfhi(wv2[r].x);
              float w2 = bflo(wv2[r].y), w3 = bfhi(wv2[r].y);
              acc[r][bi] = fmaf(w0,xv.x, fmaf(w1,xv.y, fmaf(w2,xv.z, fmaf(w3,xv.w, acc[r][bi]))));
            }
          }
        }
      }

      if (!last){
        // convoy ctx: detector = gate bk0
        if (bk == 0) detect_pub(cslot, 8, crdy, t + 1, &lfc);
        else         wait_rdy(crdy, repl, t + 1, &lfc);
        {
          float4 cr[2];
          ld2_wait(cr, (const float*)(ctx32u + par*4096) + tid*4);
          #pragma unroll
          for (int i = 0; i < 2; ++i){
            unsigned wx = __builtin_bit_cast(unsigned, cr[i].x);
            unsigned wy = __builtin_bit_cast(unsigned, cr[i].y);
            unsigned wz = __builtin_bit_cast(unsigned, cr[i].z);
            unsigned ww = __builtin_bit_cast(unsigned, cr[i].w);
            int base = i*2048 + tid*4;
            int z = base >> 11, b = (base >> 7) & 15, j = base & 127;
            float* d = lh + (z*16 + b)*CT_STR + 2*j;
            d[0] = bflo(wx); d[1] = bfhi(wx); d[2] = bflo(wy); d[3] = bfhi(wy);
            d[4] = bflo(wz); d[5] = bfhi(wz); d[6] = bflo(ww); d[7] = bfhi(ww);
          }
        }
        __syncthreads();
        #pragma unroll
        for (int it = 0; it < 4; ++it){
          int k = it*64 + klane4;
          float4 wv[4];
          #pragma unroll
          for (int r = 0; r < 4; ++r) wv[r] = bf4(*reinterpret_cast<const uint2*>(wihb[r] + 128 + (k>>1)));
          #pragma unroll
          for (int bi = 0; bi < 4; ++bi){
            float4 xv = *reinterpret_cast<const float4*>(lh + (size_t)(b4*4 + bi)*CT_STR + k);
            #pragma unroll
            for (int r = 0; r < 4; ++r)
              acc[r][bi] = fmaf(wv[r].x,xv.x, fmaf(wv[r].y,xv.y, fmaf(wv[r].z,xv.z, fmaf(wv[r].w,xv.w, acc[r][bi]))));
          }
        }
        #pragma unroll
        for (int it = 0; it < 4; ++it){
          int k = it*64 + klane4;
          float4 wv[4];
          #pragma unroll
          for (int r = 0; r < 4; ++r) wv[r] = bf4(*reinterpret_cast<const uint2*>(wihb[r] + 256 + (k>>1)));
          #pragma unroll
          for (int bi = 0; bi < 4; ++bi){
            float4 xv = *reinterpret_cast<const float4*>(lh + (size_t)(16 + b4*4 + bi)*CT_STR + k);
            #pragma unroll
            for (int r = 0; r < 4; ++r)
              acc[r][bi] = fmaf(wv[r].x,xv.x, fmaf(wv[r].y,xv.y, fmaf(wv[r].z,xv.z, fmaf(wv[r].w,xv.w, acc[r][bi]))));
          }
        }
        cell_and_publish(acc, (t + 1) & 1, t + 2, false);
      }
    } else {
      // ---------------- chain blocks ----------------
      // convoy x1: detector = chain cid0
      if (cid == 0) detect_pub(xslot, 32, hrdy + 8*16, t + 1, &lfx);   // reuse pad? no — use own
      else          wait_rdy(wsi + IW_XRDY, repl, t + 1, &lfx);
      if (cid == 0 && tid < 8) st_rlx(wsi + IW_XRDY + tid*16, t + 1);  // publish x1 replicas
      __syncthreads();
      cbar();
      if (tid < 256) x1l[tid] = ldf_c(x1m + par*4096 + cb*256 + tid);
      __syncthreads();
      {
        int hf = tid & 1;
        const float* x1b = x1l + hf*128;
        float a = 0.f;
        #pragma unroll
        for (int i = 0; i < 32; ++i){
          float4 xv = *(const float4*)(x1b + i*4);
          a = fmaf(w2r[i].x,xv.x, fmaf(w2r[i].y,xv.y, fmaf(w2r[i].z,xv.z, fmaf(w2r[i].w,xv.w, a))));
        }
        x2p[tid] = a;
      }
      __syncthreads();
      if (tid < 256) x2l[tid] = ftanh(x2p[2*tid] + x2p[2*tid + 1]);
      __syncthreads();
      if (tid < 384){
        int r = tid >> 4, ks = tid & 15;
        const float* wr = Wlin + (size_t)r*256 + ks*16;
        const float* xb = x2l + ks*16;
        float s = 0.f;
        #pragma unroll
        for (int k = 0; k < 16; ++k) s = fmaf(xb[k], wr[k], s);
        outp[tid] = s;
      }
      __syncthreads();
      if (tid < 24){
        float s = blin[tid];
        #pragma unroll
        for (int j = 0; j < 16; ++j) s += outp[tid*16 + j];
        outl[tid] = s;
      }
      __syncthreads();
      if (tid < 8){
        float w = outl[tid];
        float mx = w;
        mx = fmaxf(mx, __shfl_xor(mx, 1)); mx = fmaxf(mx, __shfl_xor(mx, 2)); mx = fmaxf(mx, __shfl_xor(mx, 4));
        float e = __expf(w - mx);
        float sum = e;
        sum += __shfl_xor(sum, 1); sum += __shfl_xor(sum, 2); sum += __shfl_xor(sum, 4);
        mixw[tid] = e * frcp(sum);
        float cm1 = (float)s_cond - 1.0f;
        float dl = sigm(outl[8 + tid]) + 0.005f;
        float lc = locl[tid] + dl;
        mixlc[tid] = lc;
        locl[tid]  = fminf(lc, cm1);
        mixis[tid] = 1.0f + __expf(-outl[16 + tid]);
      }
      __syncthreads();
      {
        float ef = (float)tid;
        float a = 0.f;
        #pragma unroll
        for (int m = 0; m < 8; ++m){
          float df = mixlc[m] - ef;
          a += (ftanh((df + 0.5f)*mixis[m]) - ftanh((df - 0.5f)*mixis[m])) * mixw[m];
        }
        a *= 0.5f;
        bool valid = (tid < s_cond) && (t < s_olen);
        if (!valid) a = 0.f;
        albl[tid] = a;
        if (hf2 == 0)
          out[CTXOUT + (size_t)cb*((size_t)DECx*ENCx) + (size_t)t*ENCx + tid] = a;
      }
      __syncthreads();
      {
        // ctx/nctx half from bf16 enc: d = hf2*128 + dl
        int dl = tid & 127, eg = tid >> 7;
        const unsigned* encbB = wsEncB + (size_t)cb*(512*128) + hf2*64 + (dl >> 1);
        const int hi = dl & 1;
        float ca = 0.f, na = 0.f;
        #pragma unroll 4
        for (int i = 0; i < 128; ++i){
          int e = eg*128 + i;
          float av = albl[e];
          float nv = albl[(e + 511) & 511];
          unsigned w = encbB[(size_t)e*128];
          float ev = hi ? bfhi(w) : bflo(w);
          ca = fmaf(av, ev, ca);
          na = fmaf(nv, ev, na);
        }
        cpn[0][eg][dl] = ca;
        cpn[1][eg][dl] = na;
      }
      __syncthreads();
      if (tid < 256){
        int z = tid >> 7, dd = tid & 127;
        float s = cpn[z][0][dd] + cpn[z][1][dd] + cpn[z][2][dd] + cpn[z][3][dd];
        x2p[z*128 + dd] = s;
        if (z == 0)
          out[(size_t)cb*((size_t)DECx*Dx) + (size_t)t*Dx + hf2*128 + dd] = s;
      }
      __syncthreads();
      if (tid < 128){
        int z = tid >> 6, j = tid & 63;
        unsigned w = pack_bf16(x2p[z*128 + 2*j], x2p[z*128 + 2*j + 1]);
        st_rlx_u32(ctx32u + par*4096 + z*2048 + cb*128 + hf2*64 + j, w);
      }
      __syncthreads();
      if (tid == 0) st_rlx(cslot + cid, t + 1);
    }
  }
}

extern "C" void kernel_launch(void* const* d_in, const int* in_sizes, int n_in,
                              void* d_out, int out_size, void* d_ws, size_t ws_size,
                              hipStream_t stream)
{
  const float* enc    = (const float*)d_in[0];
  const float* mel    = (const float*)d_in[1];
  const int*   outlen = (const int*)d_in[3];
  const int*   cond   = (const int*)d_in[4];
  const float* Wih    = (const float*)d_in[5];
  const float* Whh    = (const float*)d_in[6];
  const float* bih    = (const float*)d_in[7];
  const float* bhh    = (const float*)d_in[8];
  const float* W1     = (const float*)d_in[9];
  const float* b1v    = (const float*)d_in[10];
  const float* W2     = (const float*)d_in[11];
  const float* Wlin   = (const float*)d_in[12];
  const float* blin   = (const float*)d_in[13];
  float* outp = (float*)d_out;
  float* wsf  = (float*)d_ws;

  (void)hipFuncSetAttribute((const void*)gmm_main,
                            hipFuncAttributeMaxDynamicSharedMemorySize,
                            (int)SMEM_BYTES);

  hipLaunchKernelGGL(gmm_init, dim3(256), dim3(256), 0, stream, Wih, enc, wsf);

  void* args[] = {
    (void*)&enc, (void*)&mel, (void*)&outlen, (void*)&cond,
    (void*)&Wih, (void*)&Whh, (void*)&bih, (void*)&bhh,
    (void*)&W1, (void*)&b1v, (void*)&W2, (void*)&Wlin, (void*)&blin,
    (void*)&outp, (void*)&wsf
  };
  (void)hipLaunchCooperativeKernel((void*)gmm_main, dim3(NBLK), dim3(NTHR),
                                   args, SMEM_BYTES, stream);
}

// Round 17
// 49869.678 us; speedup vs baseline: 1.3628x; 1.3628x over previous
//
#include <hip/hip_runtime.h>
#include <stdint.h>

#define DEV static __device__ __forceinline__

namespace {
constexpr int Bx = 16, ENCx = 512, DECx = 800, Dx = 256, Hx = 1024;
constexpr int NGATE = 128, NCHAIN = 32, NBLK = NGATE + NCHAIN, NTHR = 512;

// ---- workspace float offsets ----
constexpr int WS_HBH  = 0;                 // 2 buf x 16384 ushort (bf16 h)
constexpr int WS_CTXH = WS_HBH + 16384;    // 2 buf x 8192 ushort (bf16 ctx|nctx)
constexpr int WS_X1M  = WS_CTXH + 8192;    // 2 x [16][256] fp32
constexpr int WS_FEND = WS_X1M + 8192;
// ---- int offsets (relative to wsf + WS_FEND) ----
constexpr int IW_HSLOT = 0;
constexpr int IW_XSLOT = 128;
constexpr int IW_CSLOT = 256;
constexpr int IW_HRDY  = 320;              // 8 replicas, stride 16
constexpr int IW_XRDY  = 448;
constexpr int IW_CRDY  = 576;
constexpr int IW_END   = 704;
constexpr size_t CTXOUT = (size_t)Bx*DECx*Dx;

// ---- dynamic LDS float offsets ----
constexpr int LH_STR = 1028;               // padded h stride (fp32)
constexpr int CT_STR = 260;                // padded ctx stride
constexpr int LW_H   = 0;                  // 16*1028 fp32
constexpr int LW_WHH = LW_H + 16*LH_STR;   // 32 rows x 512 uints (bf16 Whh)
constexpr int LDS_DYN_F = LW_WHH + 16384;
constexpr size_t SMEM_BYTES = (size_t)LDS_DYN_F * 4;   // 131,328 B
}

DEV float frcp(float x){ return __builtin_amdgcn_rcpf(x); }
DEV float sigm(float x){ return frcp(1.0f + __expf(-x)); }
DEV float ftanh(float x){
  x = fminf(fmaxf(x, -15.0f), 15.0f);
  float e = __expf(2.0f*x);
  return (e - 1.0f) * frcp(e + 1.0f);
}
DEV float wred16(float v){
  v += __shfl_xor(v, 1); v += __shfl_xor(v, 2);
  v += __shfl_xor(v, 4); v += __shfl_xor(v, 8);
  return v;
}
DEV int   ld_rlx(const int* p){ return __hip_atomic_load(p, __ATOMIC_RELAXED, __HIP_MEMORY_SCOPE_AGENT); }
DEV unsigned ld_rlx_u32(const unsigned* p){ return __hip_atomic_load(p, __ATOMIC_RELAXED, __HIP_MEMORY_SCOPE_AGENT); }
DEV void  st_rlx(int* p, int v){ __hip_atomic_store(p, v, __ATOMIC_RELAXED, __HIP_MEMORY_SCOPE_AGENT); }
DEV void  st_rlx_u32(unsigned* p, unsigned v){ __hip_atomic_store(p, v, __ATOMIC_RELAXED, __HIP_MEMORY_SCOPE_AGENT); }
DEV float ldf_c(const float* p){ return __hip_atomic_load(p, __ATOMIC_RELAXED, __HIP_MEMORY_SCOPE_AGENT); }
DEV void  stf_c(float* p, float v){ __hip_atomic_store(p, v, __ATOMIC_RELAXED, __HIP_MEMORY_SCOPE_AGENT); }
DEV void cbar(){ asm volatile("" ::: "memory"); }

// bf16 pack (round-nearest-even) / unpack (exact shift)
DEV unsigned pack_bf16(float lo, float hi){
  unsigned a = __builtin_bit_cast(unsigned, lo);
  unsigned b = __builtin_bit_cast(unsigned, hi);
  a += 0x7FFFu + ((a >> 16) & 1u);
  b += 0x7FFFu + ((b >> 16) & 1u);
  return (a >> 16) | (b & 0xFFFF0000u);
}
DEV float bflo(unsigned w){ return __builtin_bit_cast(float, w << 16); }
DEV float bfhi(unsigned w){ return __builtin_bit_cast(float, w & 0xFFFF0000u); }

// sc1 bulk loads: issue + wait inside one asm block
DEV void ld4_wait(float4 (&r)[4], const float* p){
  const float *a1=p+2048,*a2=p+4096,*a3=p+6144;
  asm volatile(
    "global_load_dwordx4 %0, %4, off sc1\n\t"
    "global_load_dwordx4 %1, %5, off sc1\n\t"
    "global_load_dwordx4 %2, %6, off sc1\n\t"
    "global_load_dwordx4 %3, %7, off sc1\n\t"
    "s_waitcnt vmcnt(0)"
    : "=&v"(r[0]),"=&v"(r[1]),"=&v"(r[2]),"=&v"(r[3])
    : "v"(p),"v"(a1),"v"(a2),"v"(a3)
    : "memory");
}
DEV void ld2_wait(float4 (&r)[2], const float* p){
  const float *a1=p+2048;
  asm volatile(
    "global_load_dwordx4 %0, %2, off sc1\n\t"
    "global_load_dwordx4 %1, %3, off sc1\n\t"
    "s_waitcnt vmcnt(0)"
    : "=&v"(r[0]),"=&v"(r[1])
    : "v"(p),"v"(a1)
    : "memory");
}
DEV int4 ld4i_sc1(const int* p){
  int4 r;
  asm volatile("global_load_dwordx4 %0, %1, off sc1\n\ts_waitcnt vmcnt(0)"
    : "=&v"(r) : "v"(p) : "memory");
  return r;
}

// waiter: wave0 polls its replica (tight cadence), stamps LDS; other waves spin LDS
DEV void wait_rdy(int* rdy8, int repl, int target, volatile int* lslot){
  const int tid = threadIdx.x;
  if (tid < 64){
    while (ld_rlx(rdy8 + repl*16) < target) __builtin_amdgcn_s_sleep(2);
    if (tid == 0) *lslot = target;
  } else {
    while (*lslot < target) __builtin_amdgcn_s_sleep(1);
  }
  __syncthreads();
  cbar();
}

// detector: wave0 scans nq*4 slots with dwordx4, then publishes 8 replicas
DEV void detect_pub(int* slots, int nq, int* rdy8, int target, volatile int* lslot){
  const int tid = threadIdx.x;
  if (tid < 64){
    const int* my = slots + tid*4;
    const bool active = (tid < nq);
    for (;;){
      bool ok = true;
      if (active){
        int4 v = ld4i_sc1(my);
        ok = (v.x >= target) & (v.y >= target) & (v.z >= target) & (v.w >= target);
      }
      if (__ballot(ok) == ~0ull) break;
      __builtin_amdgcn_s_sleep(2);
    }
    if (tid < 8) st_rlx(rdy8 + tid*16, target);
    if (tid == 0) *lslot = target;
  } else {
    while (*lslot < target) __builtin_amdgcn_s_sleep(1);
  }
  __syncthreads();
  cbar();
}

extern "C" __global__ void gmm_init(float* wsf){
  int* wsi = (int*)(wsf + WS_FEND);
  int idx = blockIdx.x*blockDim.x + threadIdx.x;
  for (int k = idx; k < IW_END; k += gridDim.x*blockDim.x) wsi[k] = 0;
}

extern "C" __global__ void __launch_bounds__(NTHR, 1) gmm_main(
    const float* __restrict__ enc, const float* __restrict__ mel,
    const int* __restrict__ outlen, const int* __restrict__ condlen,
    const float* __restrict__ Wih, const float* __restrict__ Whh,
    const float* __restrict__ bih, const float* __restrict__ bhh,
    const float* __restrict__ W1,  const float* __restrict__ b1v,
    const float* __restrict__ W2,  const float* __restrict__ Wlin,
    const float* __restrict__ blin,
    float* __restrict__ out, float* __restrict__ wsf)
{
  const int bk = blockIdx.x, tid = threadIdx.x;
  const int klane4 = (tid & 15) * 4;
  const int b4 = (tid >> 4) & 3;
  const int wid = tid >> 6;

  int* wsi   = (int*)(wsf + WS_FEND);
  int* hslot = wsi + IW_HSLOT;
  int* xslot = wsi + IW_XSLOT;
  int* cslot = wsi + IW_CSLOT;
  int* hrdy  = wsi + IW_HRDY;
  int* xrdy  = wsi + IW_XRDY;
  int* crdy  = wsi + IW_CRDY;
  unsigned short* hbh = (unsigned short*)(wsf + WS_HBH);   // 2 x 16384 ushort
  unsigned* ctx32u    = (unsigned*)(wsf + WS_CTXH);        // 2 x 4096 uints
  float* x1m = wsf + WS_X1M;                               // 2 x 4096 fp32

  extern __shared__ float lds[];
  float*    lh      = lds + LW_H;
  unsigned* lwhh_u  = (unsigned*)(lds + LW_WHH);
  const uint2* lwhh2 = (const uint2*)(lds + LW_WHH);

  __shared__ float g_lds[512];
  __shared__ float bsum[32];
  __shared__ float cl[128];
  __shared__ float hstg[128];
  __shared__ float x1l[256];
  __shared__ float x2p[512];
  __shared__ float x2l[256];
  __shared__ float outp[384];
  __shared__ float outl[24];
  __shared__ float mixw[8], mixlc[8], mixis[8];
  __shared__ float locl[8];
  __shared__ float albl[512];
  __shared__ float cpn[2][4][128];
  __shared__ int   s_cond, s_olen;
  __shared__ int   lfh, lfx, lfc;

  if (tid == 0){ lfh = 0; lfx = 0; lfc = 0; }

  const bool is_gate = (bk < NGATE);
  const int  cid = bk - NGATE;
  const int  cb  = cid >> 1;
  const int  hf2 = cid & 1;
  const int  repl = bk & 7;

  // gate: local rows r (0..31): global gate row = (r>>3)*1024 + bk*8 + (r&7)
  const int r0 = wid*4;
  const float* wih[4];
  if (is_gate){
    #pragma unroll
    for (int r = 0; r < 4; ++r){
      int lr = r0 + r;
      wih[r] = Wih + (size_t)((lr>>3)*1024 + bk*8 + (lr&7))*768;
    }
  }

  // ---------------- one-time staging ----------------
  float4 w2r[32];
  if (is_gate){
    for (int i = tid; i < 16384; i += NTHR){
      int r = i >> 9, c = i & 511;
      size_t gr = (size_t)((r>>3)*1024 + bk*8 + (r&7));
      lwhh_u[i] = pack_bf16(Whh[gr*1024 + 2*c], Whh[gr*1024 + 2*c + 1]);
    }
    if (tid < 32){
      int g = tid >> 3, u = bk*8 + (tid & 7);
      bsum[tid] = bih[g*1024 + u] + bhh[g*1024 + u];
    }
  } else {
    if (tid == 0){ s_cond = condlen[cb]; s_olen = outlen[cb]; }
    if (tid < 8) locl[tid] = -0.1f;
    int r = tid >> 1, hf = tid & 1;
    const float* w2row = W2 + (size_t)r*256 + hf*128;
    #pragma unroll
    for (int i = 0; i < 32; ++i) w2r[i] = *reinterpret_cast<const float4*>(w2row + i*4);
  }
  __syncthreads();

  // gates: stage bf16 h master -> LDS fp32 (32 KB sc1)
  auto write_h = [&](int t){
    float4 r[4];
    ld4_wait(r, (const float*)(hbh + (t & 1)*16384) + tid*4);
    #pragma unroll
    for (int i = 0; i < 4; ++i){
      unsigned wx = __builtin_bit_cast(unsigned, r[i].x);
      unsigned wy = __builtin_bit_cast(unsigned, r[i].y);
      unsigned wz = __builtin_bit_cast(unsigned, r[i].z);
      unsigned ww = __builtin_bit_cast(unsigned, r[i].w);
      int b = i*4 + (tid >> 7);
      float* d = lh + b*LH_STR + (tid & 127)*8;
      d[0] = bflo(wx); d[1] = bfhi(wx); d[2] = bflo(wy); d[3] = bfhi(wy);
      d[4] = bflo(wz); d[5] = bfhi(wz); d[6] = bflo(ww); d[7] = bfhi(ww);
    }
    __syncthreads();
  };

  // gate reduce + cell + bf16 h publish (writes buffer bsel, stamps hslot with stamp)
  auto cell_and_publish = [&](float (&acc)[4][4], int bsel, int stamp, bool first){
    #pragma unroll
    for (int r = 0; r < 4; ++r)
      #pragma unroll
      for (int bi = 0; bi < 4; ++bi){
        float v = wred16(acc[r][bi]);
        if ((tid & 15) == 0) g_lds[(r0 + r)*16 + b4*4 + bi] = v;
      }
    __syncthreads();
    if (tid < 128){
      int u = tid >> 4, b = tid & 15;
      float gi = g_lds[( 0 + u)*16 + b] + bsum[u];
      float gg = g_lds[(16 + u)*16 + b] + bsum[16 + u];
      float go = g_lds[(24 + u)*16 + b] + bsum[24 + u];
      float c2;
      if (first){
        c2 = sigm(gi) * ftanh(gg);
      } else {
        float gf = g_lds[(8 + u)*16 + b] + bsum[8 + u];
        c2 = sigm(gf)*cl[tid] + sigm(gi)*ftanh(gg);
      }
      float h2 = sigm(go)*ftanh(c2);
      cl[tid] = c2;
      hstg[u*16 + b] = h2;
    }
    __syncthreads();
    if (tid < 64){
      int p = tid >> 4, b = tid & 15;
      unsigned w = pack_bf16(hstg[(2*p)*16 + b], hstg[(2*p + 1)*16 + b]);
      st_rlx_u32((unsigned*)hbh + bsel*8192 + b*512 + bk*4 + p, w);
    }
    __syncthreads();                     // drain: h at coherence point
    if (tid == 0) st_rlx(hslot + bk, stamp);
  };

  // ---------------- prologue: gates t=0 (q=[mel0, 0, enc[:,0,:]], h=0, c=0) -> h_0
  if (is_gate){
    float acc[4][4] = {};
    #pragma unroll
    for (int it = 0; it < 4; ++it){
      int k = it*64 + klane4;
      float4 wv[4];
      #pragma unroll
      for (int r = 0; r < 4; ++r) wv[r] = *reinterpret_cast<const float4*>(wih[r] + k);
      #pragma unroll
      for (int bi = 0; bi < 4; ++bi){
        float4 xv = *reinterpret_cast<const float4*>(mel + (size_t)(b4*4 + bi)*DECx*Dx + k);
        #pragma unroll
        for (int r = 0; r < 4; ++r)
          acc[r][bi] = fmaf(wv[r].x,xv.x, fmaf(wv[r].y,xv.y, fmaf(wv[r].z,xv.z, fmaf(wv[r].w,xv.w, acc[r][bi]))));
      }
    }
    #pragma unroll
    for (int it = 0; it < 4; ++it){
      int k = it*64 + klane4;
      float4 wv[4];
      #pragma unroll
      for (int r = 0; r < 4; ++r) wv[r] = *reinterpret_cast<const float4*>(wih[r] + 512 + k);
      #pragma unroll
      for (int bi = 0; bi < 4; ++bi){
        float4 xv = *reinterpret_cast<const float4*>(enc + (size_t)(b4*4 + bi)*ENCx*Dx + k);
        #pragma unroll
        for (int r = 0; r < 4; ++r)
          acc[r][bi] = fmaf(wv[r].x,xv.x, fmaf(wv[r].y,xv.y, fmaf(wv[r].z,xv.z, fmaf(wv[r].w,xv.w, acc[r][bi]))));
      }
    }
    cell_and_publish(acc, 0, 1, true);
  }

  // ---------------- main loop ----------------
  for (int t = 0; t < DECx; ++t){
    const int par = t & 1;
    const bool last = (t == DECx - 1);

    if (is_gate){
      // ---- convoy 1: h_t ready
      if (bk == 0) detect_pub(hslot, 32, hrdy, t + 1, &lfh);
      else         wait_rdy(hrdy, repl, t + 1, &lfh);
      write_h(t);

      // ---- x1 rows 2bk, 2bk+1 (h local)
      {
        int row = tid >> 8;
        int b = (tid >> 4) & 15, kl = tid & 15;
        const float* W1r = W1 + (size_t)(2*bk + row)*1024;
        float a = 0.f;
        #pragma unroll
        for (int it = 0; it < 16; ++it){
          int k = it*64 + kl*4;
          float4 wv = *reinterpret_cast<const float4*>(W1r + k);
          float4 xv = *reinterpret_cast<const float4*>(lh + (size_t)b*LH_STR + k);
          a = fmaf(wv.x,xv.x, fmaf(wv.y,xv.y, fmaf(wv.z,xv.z, fmaf(wv.w,xv.w, a))));
        }
        a = wred16(a);
        if (kl == 0){
          a += b1v[2*bk + row];
          a = (a >= 0.f) ? a : 0.1f*a;
          stf_c(x1m + par*4096 + b*256 + 2*bk + row, a);
        }
      }
      __syncthreads();                   // drain: x1 at coherence point
      if (tid == 0) st_rlx(xslot + bk, t + 1);

      // ---- region 1 (overlaps chain): mel_{t+1} + Whh(bf16 LDS) @ h_t
      float acc[4][4] = {};
      if (!last){
        const int tt = t + 1;
        #pragma unroll
        for (int it = 0; it < 4; ++it){
          int k = it*64 + klane4;
          float4 wv[4];
          #pragma unroll
          for (int r = 0; r < 4; ++r) wv[r] = *reinterpret_cast<const float4*>(wih[r] + k);
          #pragma unroll
          for (int bi = 0; bi < 4; ++bi){
            float4 xv = *reinterpret_cast<const float4*>(mel + ((size_t)(b4*4 + bi)*DECx + tt)*Dx + k);
            #pragma unroll
            for (int r = 0; r < 4; ++r)
              acc[r][bi] = fmaf(wv[r].x,xv.x, fmaf(wv[r].y,xv.y, fmaf(wv[r].z,xv.z, fmaf(wv[r].w,xv.w, acc[r][bi]))));
          }
        }
        #pragma unroll 4
        for (int it = 0; it < 16; ++it){
          int k = it*64 + klane4;
          uint2 wv2[4];
          #pragma unroll
          for (int r = 0; r < 4; ++r) wv2[r] = lwhh2[(size_t)(r0 + r)*256 + it*16 + (tid & 15)];
          #pragma unroll
          for (int bi = 0; bi < 4; ++bi){
            float4 xv = *reinterpret_cast<const float4*>(lh + (size_t)(b4*4 + bi)*LH_STR + k);
            #pragma unroll
            for (int r = 0; r < 4; ++r){
              float w0 = bflo(wv2[r].x), w1 = bfhi(wv2[r].x);
              float w2 = bflo(wv2[r].y), w3 = bfhi(wv2[r].y);
              acc[r][bi] = fmaf(w0,xv.x, fmaf(w1,xv.y, fmaf(w2,xv.z, fmaf(w3,xv.w, acc[r][bi]))));
            }
          }
        }
      }

      if (!last){
        // ---- convoy 3: ctx_t ready
        if (bk == 0) detect_pub(cslot, 8, crdy, t + 1, &lfc);
        else         wait_rdy(crdy, repl, t + 1, &lfc);
        // stage bf16 ctx|nctx -> LDS fp32
        {
          float4 cr[2];
          ld2_wait(cr, (const float*)(ctx32u + par*4096) + tid*4);
          #pragma unroll
          for (int i = 0; i < 2; ++i){
            unsigned wx = __builtin_bit_cast(unsigned, cr[i].x);
            unsigned wy = __builtin_bit_cast(unsigned, cr[i].y);
            unsigned wz = __builtin_bit_cast(unsigned, cr[i].z);
            unsigned ww = __builtin_bit_cast(unsigned, cr[i].w);
            int base = i*2048 + tid*4;
            int z = base >> 11, b = (base >> 7) & 15, j = base & 127;
            float* d = lh + (z*16 + b)*CT_STR + 2*j;
            d[0] = bflo(wx); d[1] = bfhi(wx); d[2] = bflo(wy); d[3] = bfhi(wy);
            d[4] = bflo(wz); d[5] = bfhi(wz); d[6] = bflo(ww); d[7] = bfhi(ww);
          }
        }
        __syncthreads();
        // region 2: Wih cols 256..767 @ [ctx | nctx]
        #pragma unroll
        for (int it = 0; it < 4; ++it){
          int k = it*64 + klane4;
          float4 wv[4];
          #pragma unroll
          for (int r = 0; r < 4; ++r) wv[r] = *reinterpret_cast<const float4*>(wih[r] + 256 + k);
          #pragma unroll
          for (int bi = 0; bi < 4; ++bi){
            float4 xv = *reinterpret_cast<const float4*>(lh + (size_t)(b4*4 + bi)*CT_STR + k);
            #pragma unroll
            for (int r = 0; r < 4; ++r)
              acc[r][bi] = fmaf(wv[r].x,xv.x, fmaf(wv[r].y,xv.y, fmaf(wv[r].z,xv.z, fmaf(wv[r].w,xv.w, acc[r][bi]))));
          }
        }
        #pragma unroll
        for (int it = 0; it < 4; ++it){
          int k = it*64 + klane4;
          float4 wv[4];
          #pragma unroll
          for (int r = 0; r < 4; ++r) wv[r] = *reinterpret_cast<const float4*>(wih[r] + 512 + k);
          #pragma unroll
          for (int bi = 0; bi < 4; ++bi){
            float4 xv = *reinterpret_cast<const float4*>(lh + (size_t)(16 + b4*4 + bi)*CT_STR + k);
            #pragma unroll
            for (int r = 0; r < 4; ++r)
              acc[r][bi] = fmaf(wv[r].x,xv.x, fmaf(wv[r].y,xv.y, fmaf(wv[r].z,xv.z, fmaf(wv[r].w,xv.w, acc[r][bi]))));
          }
        }
        cell_and_publish(acc, (t + 1) & 1, t + 2, false);
      }
    } else {
      // ---------------- chain blocks ----------------
      // ---- convoy 2: x1 ready
      if (bk == NGATE) detect_pub(xslot, 32, xrdy, t + 1, &lfx);
      else             wait_rdy(xrdy, repl, t + 1, &lfx);
      if (tid < 256) x1l[tid] = ldf_c(x1m + par*4096 + cb*256 + tid);
      __syncthreads();
      {
        int hf = tid & 1;
        const float* x1b = x1l + hf*128;
        float a = 0.f;
        #pragma unroll
        for (int i = 0; i < 32; ++i){
          float4 xv = *(const float4*)(x1b + i*4);
          a = fmaf(w2r[i].x,xv.x, fmaf(w2r[i].y,xv.y, fmaf(w2r[i].z,xv.z, fmaf(w2r[i].w,xv.w, a))));
        }
        x2p[tid] = a;
      }
      __syncthreads();
      if (tid < 256) x2l[tid] = ftanh(x2p[2*tid] + x2p[2*tid + 1]);
      __syncthreads();
      if (tid < 384){
        int r = tid >> 4, ks = tid & 15;
        const float* wr = Wlin + (size_t)r*256 + ks*16;
        const float* xb = x2l + ks*16;
        float s = 0.f;
        #pragma unroll
        for (int k = 0; k < 16; ++k) s = fmaf(xb[k], wr[k], s);
        outp[tid] = s;
      }
      __syncthreads();
      if (tid < 24){
        float s = blin[tid];
        #pragma unroll
        for (int j = 0; j < 16; ++j) s += outp[tid*16 + j];
        outl[tid] = s;
      }
      __syncthreads();
      if (tid < 8){
        float w = outl[tid];
        float mx = w;
        mx = fmaxf(mx, __shfl_xor(mx, 1)); mx = fmaxf(mx, __shfl_xor(mx, 2)); mx = fmaxf(mx, __shfl_xor(mx, 4));
        float e = __expf(w - mx);
        float sum = e;
        sum += __shfl_xor(sum, 1); sum += __shfl_xor(sum, 2); sum += __shfl_xor(sum, 4);
        mixw[tid] = e * frcp(sum);
        float cm1 = (float)s_cond - 1.0f;
        float dl = sigm(outl[8 + tid]) + 0.005f;
        float lc = locl[tid] + dl;
        mixlc[tid] = lc;
        locl[tid]  = fminf(lc, cm1);
        mixis[tid] = 1.0f + __expf(-outl[16 + tid]);
      }
      __syncthreads();
      {
        float ef = (float)tid;
        float a = 0.f;
        #pragma unroll
        for (int m = 0; m < 8; ++m){
          float df = mixlc[m] - ef;
          a += (ftanh((df + 0.5f)*mixis[m]) - ftanh((df - 0.5f)*mixis[m])) * mixw[m];
        }
        a *= 0.5f;
        bool valid = (tid < s_cond) && (t < s_olen);
        if (!valid) a = 0.f;
        albl[tid] = a;
        if (hf2 == 0)
          out[CTXOUT + (size_t)cb*((size_t)DECx*ENCx) + (size_t)t*ENCx + tid] = a;
      }
      __syncthreads();
      {
        // ctx/nctx half: d = hf2*128 + dl
        int dl = tid & 127, eg = tid >> 7;
        const float* encb = enc + (size_t)cb*ENCx*Dx + hf2*128;
        float ca = 0.f, na = 0.f;
        #pragma unroll 4
        for (int i = 0; i < 128; ++i){
          int e = eg*128 + i;
          float av = albl[e];
          float nv = albl[(e + 511) & 511];
          float ev = encb[(size_t)e*256 + dl];
          ca = fmaf(av, ev, ca);
          na = fmaf(nv, ev, na);
        }
        cpn[0][eg][dl] = ca;
        cpn[1][eg][dl] = na;
      }
      __syncthreads();
      if (tid < 256){
        int z = tid >> 7, dd = tid & 127;
        float s = cpn[z][0][dd] + cpn[z][1][dd] + cpn[z][2][dd] + cpn[z][3][dd];
        x2p[z*128 + dd] = s;               // stage for bf16 pack
        if (z == 0)
          out[(size_t)cb*((size_t)DECx*Dx) + (size_t)t*Dx + hf2*128 + dd] = s;
      }
      __syncthreads();
      if (tid < 128){
        int z = tid >> 6, j = tid & 63;
        unsigned w = pack_bf16(x2p[z*128 + 2*j], x2p[z*128 + 2*j + 1]);
        st_rlx_u32(ctx32u + par*4096 + z*2048 + cb*128 + hf2*64 + j, w);
      }
      __syncthreads();                     // drain: ctx at coherence point
      if (tid == 0) st_rlx(cslot + cid, t + 1);
    }
  }
}

extern "C" void kernel_launch(void* const* d_in, const int* in_sizes, int n_in,
                              void* d_out, int out_size, void* d_ws, size_t ws_size,
                              hipStream_t stream)
{
  const float* enc    = (const float*)d_in[0];
  const float* mel    = (const float*)d_in[1];
  const int*   outlen = (const int*)d_in[3];
  const int*   cond   = (const int*)d_in[4];
  const float* Wih    = (const float*)d_in[5];
  const float* Whh    = (const float*)d_in[6];
  const float* bih    = (const float*)d_in[7];
  const float* bhh    = (const float*)d_in[8];
  const float* W1     = (const float*)d_in[9];
  const float* b1v    = (const float*)d_in[10];
  const float* W2     = (const float*)d_in[11];
  const float* Wlin   = (const float*)d_in[12];
  const float* blin   = (const float*)d_in[13];
  float* outp = (float*)d_out;
  float* wsf  = (float*)d_ws;

  (void)hipFuncSetAttribute((const void*)gmm_main,
                            hipFuncAttributeMaxDynamicSharedMemorySize,
                            (int)SMEM_BYTES);

  hipLaunchKernelGGL(gmm_init, dim3(16), dim3(64), 0, stream, wsf);

  void* args[] = {
    (void*)&enc, (void*)&mel, (void*)&outlen, (void*)&cond,
    (void*)&Wih, (void*)&Whh, (void*)&bih, (void*)&bhh,
    (void*)&W1, (void*)&b1v, (void*)&W2, (void*)&Wlin, (void*)&blin,
    (void*)&outp, (void*)&wsf
  };
  (void)hipLaunchCooperativeKernel((void*)gmm_main, dim3(NBLK), dim3(NTHR),
                                   args, SMEM_BYTES, stream);
}